// Round 5
// baseline (239.771 us; speedup 1.0000x reference)
//
#include <hip/hip_runtime.h>

// ExLlama q4: T=32, K=8192, N=28672, group=128.
// Harness promotes fp16 reference arrays to float32; output is float32.
#define T_TOK   32
#define KDIM    8192
#define NDIM    28672
#define NGRP    64        // K / 128
#define NZWORDS 3584      // N / 8
#define NSEG    8         // K-segments (blockIdx.y)
#define GPS     (NGRP / NSEG)   // 8 groups per segment

typedef _Float16 half8  __attribute__((ext_vector_type(8)));
typedef _Float16 half2v __attribute__((ext_vector_type(2)));
typedef float    f32x4  __attribute__((ext_vector_type(4)));
typedef unsigned uint4v __attribute__((ext_vector_type(4)));

// One wave: 64 columns (4 n-tiles of 16) x 32 tokens over one K-segment.
// MFMA 16x16x32 f16: A[m=lane&15][k=quad*8+j], B[k=quad*8+j][n=lane&15],
// C/D: col=lane&15, row=quad*4+reg.
// Within each 8-k block both A and B use k-permutation [0,4,1,5,2,6,3,7]:
//   A: v_cvt_pkrtz(x[k+i], x[k+i+4]) packs pairs (i, i+4) for free;
//   B: pair = ((w>>4i)&0x000F000F)|0x64006400 = fp16 (1024+q_i, 1024+q_{i+4});
//      b = (pair + (-(1025+z))) * s   (integer part exact in fp16).
// Split-K via fp32 hardware atomics; bias/8 folded into every segment's add
// (exact: /8 is a power of two, 8 segments sum to exactly bias).
// No LDS, no barriers; qweight/scales/zeros register double-buffered.
__global__ __launch_bounds__(256, 3)
void exllama_gemm_atomic(const int*   __restrict__ qweight,
                         const int*   __restrict__ qzeros,
                         const float* __restrict__ scales,
                         const float* __restrict__ x,
                         const float* __restrict__ bias,
                         float*       __restrict__ out)
{
    const int lane = threadIdx.x & 63;
    const int wav  = threadIdx.x >> 6;
    const int quad = lane >> 4;
    const int l16  = lane & 15;
    const int seg  = blockIdx.y;
    const int n0   = blockIdx.x * 256 + wav * 64;

    int nc[4];
    #pragma unroll
    for (int j = 0; j < 4; ++j) nc[j] = n0 + j * 16 + l16;

    f32x4 acc[4][2];
    #pragma unroll
    for (int j = 0; j < 4; ++j)
        #pragma unroll
        for (int m = 0; m < 2; ++m)
            acc[j][m] = (f32x4){0.f, 0.f, 0.f, 0.f};

    const int g0 = seg * GPS;

    // x row bases for this lane's two tokens, at quad's k sub-offset
    const float* xr0 = x + (size_t)l16 * KDIM + quad * 8;
    const float* xr1 = xr0 + (size_t)16 * KDIM;

    unsigned qw[2][16];
    half2v   sp[2][4], cp[2][4];

    auto load_group = [&](int g, int b) {
        #pragma unroll
        for (int j = 0; j < 4; ++j) {
            float s  = scales[(size_t)g * NDIM + nc[j]];
            int   zw = qzeros[(size_t)g * NZWORDS + (nc[j] >> 3)];
            int   z  = (zw >> ((nc[j] & 7) * 4)) & 15;
            _Float16 sh = (_Float16)s;
            _Float16 ch = (_Float16)(float)(-(1025 + z));
            sp[b][j] = (half2v){sh, sh};
            cp[b][j] = (half2v){ch, ch};
        }
        const size_t rb = (size_t)(g * 16 + quad) * NDIM;
        #pragma unroll
        for (int c = 0; c < 4; ++c)
            #pragma unroll
            for (int j = 0; j < 4; ++j)
                qw[b][c * 4 + j] = (unsigned)qweight[rb + (size_t)(c * 4) * NDIM + nc[j]];
    };

    auto compute_group = [&](int g, int b) {
        #pragma unroll
        for (int c = 0; c < 4; ++c) {
            const int kof = g * 128 + c * 32;    // + quad*8 already in xr
            f32x4 xa = *(const f32x4*)(xr0 + kof);
            f32x4 xb = *(const f32x4*)(xr0 + kof + 4);
            f32x4 xc = *(const f32x4*)(xr1 + kof);
            f32x4 xd = *(const f32x4*)(xr1 + kof + 4);
            uint4v u0, u1;
            #pragma unroll
            for (int i = 0; i < 4; ++i) {
                u0[i] = __builtin_bit_cast(unsigned, __builtin_amdgcn_cvt_pkrtz(xa[i], xb[i]));
                u1[i] = __builtin_bit_cast(unsigned, __builtin_amdgcn_cvt_pkrtz(xc[i], xd[i]));
            }
            half8 a0 = __builtin_bit_cast(half8, u0);
            half8 a1 = __builtin_bit_cast(half8, u1);
            #pragma unroll
            for (int j = 0; j < 4; ++j) {
                const unsigned w = qw[b][c * 4 + j];
                uint4v bu;
                #pragma unroll
                for (int i = 0; i < 4; ++i) {
                    unsigned t = ((w >> (4 * i)) & 0x000F000Fu) | 0x64006400u;
                    half2v th = __builtin_bit_cast(half2v, t);
                    half2v r  = (th + cp[b][j]) * sp[b][j];
                    bu[i] = __builtin_bit_cast(unsigned, r);
                }
                half8 bf = __builtin_bit_cast(half8, bu);
                acc[j][0] = __builtin_amdgcn_mfma_f32_16x16x32_f16(a0, bf, acc[j][0], 0, 0, 0);
                acc[j][1] = __builtin_amdgcn_mfma_f32_16x16x32_f16(a1, bf, acc[j][1], 0, 0, 0);
            }
        }
    };

    load_group(g0, 0);
    #pragma unroll 1
    for (int gi = 0; gi < GPS; gi += 2) {
        load_group(g0 + gi + 1, 1);
        compute_group(g0 + gi, 0);
        if (gi + 2 < GPS) load_group(g0 + gi + 2, 0);
        compute_group(g0 + gi + 1, 1);
    }

    // Split-K accumulate: out += acc + bias/NSEG  (exact: NSEG is a power of 2)
    #pragma unroll
    for (int j = 0; j < 4; ++j) {
        const int n  = n0 + j * 16 + l16;
        const float bb = bias[n] * (1.0f / NSEG);
        #pragma unroll
        for (int m = 0; m < 2; ++m)
            #pragma unroll
            for (int r = 0; r < 4; ++r) {
                const int t = m * 16 + quad * 4 + r;
                unsafeAtomicAdd(out + (size_t)t * NDIM + n, acc[j][m][r] + bb);
            }
    }
}

extern "C" void kernel_launch(void* const* d_in, const int* in_sizes, int n_in,
                              void* d_out, int out_size, void* d_ws, size_t ws_size,
                              hipStream_t stream)
{
    const float* x  = (const float*)d_in[0];   // (32, 8192) f32 (fp16 promoted)
    const int* qweight = (const int*)d_in[1];  // (1024, 28672) i32
    const int* qzeros  = (const int*)d_in[2];  // (64, 3584) i32
    const float* sc = (const float*)d_in[3];   // (64, 28672) f32
    const float* bs = (const float*)d_in[4];   // (28672,) f32
    float* out      = (float*)d_out;           // (32, 28672) f32
    (void)d_ws; (void)ws_size;

    exllama_gemm_atomic<<<dim3(NDIM / 256, NSEG), 256, 0, stream>>>(
        qweight, qzeros, sc, x, bs, out);
}

// Round 6
// 217.419 us; speedup vs baseline: 1.1028x; 1.1028x over previous
//
#include <hip/hip_runtime.h>

// ExLlama q4: T=32, K=8192, N=28672, group=128.
// Harness promotes fp16 reference arrays to float32; output is float32.
#define T_TOK   32
#define KDIM    8192
#define NDIM    28672
#define NGRP    64        // K / 128
#define NZWORDS 3584      // N / 8
#define NSEG    16        // K-segments (blockIdx.y)
#define SEGK    (KDIM / NSEG)    // 512
#define GPS     (NGRP / NSEG)    // 4 groups per segment
#define XROW    (SEGK + 8)       // padded LDS row stride (fp16): 520

typedef _Float16 half8  __attribute__((ext_vector_type(8)));
typedef _Float16 half2v __attribute__((ext_vector_type(2)));
typedef float    f32x4  __attribute__((ext_vector_type(4)));
typedef unsigned uint4v __attribute__((ext_vector_type(4)));

// One wave: 64 columns (4 n-tiles of 16) x 32 tokens over one K-segment.
// MFMA 16x16x32 f16: A[m=lane&15][k=quad*8+j], B[k=quad*8+j][n=lane&15],
// C/D: col=lane&15, row=quad*4+reg.
// Within each 8-k block both A and B use k-permutation [0,4,1,5,2,6,3,7]:
//   A: packed at LDS-staging time (free);
//   B: pair = ((w>>4i)&0x000F000F)|0x64006400 = fp16 (1024+q_i, 1024+q_{i+4});
//      b = (pair + (-(1025+z))) * s   (integer part exact in fp16).
// CRITICAL structure: steady-state loop has ONLY qweight/scale/zero global
// loads (register double-buffered, vmcnt stays >0); x comes from LDS
// (lgkmcnt — independent counter), so the prefetch queue is never drained.
// Split-K via fp32 HW atomics; bias/NSEG folded into every segment (exact).
__global__ __launch_bounds__(256)
void exllama_gemm_lds_atomic(const int*   __restrict__ qweight,
                             const int*   __restrict__ qzeros,
                             const float* __restrict__ scales,
                             const float* __restrict__ x,
                             const float* __restrict__ bias,
                             float*       __restrict__ out)
{
    __shared__ alignas(16) _Float16 xs[T_TOK * XROW];   // 33.3 KB -> 4 blocks/CU

    const int tid  = threadIdx.x;
    const int lane = tid & 63;
    const int wav  = tid >> 6;
    const int quad = lane >> 4;
    const int l16  = lane & 15;
    const int seg  = blockIdx.y;
    const int n0   = blockIdx.x * 256 + wav * 64;

    // ---- stage x segment into LDS as fp16, pair-permuted [i, i+4] ----
    {
        const int kseg0 = seg * SEGK;
        #pragma unroll
        for (int it = 0; it < (T_TOK * SEGK) / (256 * 8); ++it) {   // 8 iters
            const int e  = it * 2048 + tid * 8;
            const int t  = e >> 9;           // SEGK = 512
            const int kl = e & (SEGK - 1);
            const float* xp = x + (size_t)t * KDIM + kseg0 + kl;
            f32x4 lo = *(const f32x4*)xp;
            f32x4 hi = *(const f32x4*)(xp + 4);
            uint4v u;
            #pragma unroll
            for (int j = 0; j < 4; ++j)
                u[j] = __builtin_bit_cast(unsigned,
                          __builtin_amdgcn_cvt_pkrtz(lo[j], hi[j]));
            *(uint4v*)(xs + t * XROW + kl) = u;
        }
    }
    __syncthreads();

    int nc[4];
    #pragma unroll
    for (int j = 0; j < 4; ++j) nc[j] = n0 + j * 16 + l16;

    f32x4 acc[4][2];
    #pragma unroll
    for (int j = 0; j < 4; ++j)
        #pragma unroll
        for (int m = 0; m < 2; ++m)
            acc[j][m] = (f32x4){0.f, 0.f, 0.f, 0.f};

    const int g0 = seg * GPS;

    unsigned qw[2][16];
    half2v   sp[2][4], cp[2][4];

    auto load_group = [&](int g, int b) {
        #pragma unroll
        for (int j = 0; j < 4; ++j) {
            float s  = scales[(size_t)g * NDIM + nc[j]];
            int   zw = qzeros[(size_t)g * NZWORDS + (nc[j] >> 3)];
            int   z  = (zw >> ((nc[j] & 7) * 4)) & 15;
            _Float16 sh = (_Float16)s;
            _Float16 ch = (_Float16)(float)(-(1025 + z));
            sp[b][j] = (half2v){sh, sh};
            cp[b][j] = (half2v){ch, ch};
        }
        const size_t rb = (size_t)(g * 16 + quad) * NDIM;
        #pragma unroll
        for (int c = 0; c < 4; ++c)
            #pragma unroll
            for (int j = 0; j < 4; ++j)
                qw[b][c * 4 + j] = (unsigned)qweight[rb + (size_t)(c * 4) * NDIM + nc[j]];
    };

    auto compute_group = [&](int gi, int b) {
        #pragma unroll
        for (int c = 0; c < 4; ++c) {
            const int kloc = gi * 128 + c * 32 + quad * 8;
            half8 a0 = *(const half8*)(xs + l16 * XROW + kloc);
            half8 a1 = *(const half8*)(xs + (l16 + 16) * XROW + kloc);
            #pragma unroll
            for (int j = 0; j < 4; ++j) {
                const unsigned w = qw[b][c * 4 + j];
                uint4v bu;
                #pragma unroll
                for (int i = 0; i < 4; ++i) {
                    unsigned t = ((w >> (4 * i)) & 0x000F000Fu) | 0x64006400u;
                    half2v th = __builtin_bit_cast(half2v, t);
                    half2v r  = (th + cp[b][j]) * sp[b][j];
                    bu[i] = __builtin_bit_cast(unsigned, r);
                }
                half8 bf = __builtin_bit_cast(half8, bu);
                acc[j][0] = __builtin_amdgcn_mfma_f32_16x16x32_f16(a0, bf, acc[j][0], 0, 0, 0);
                acc[j][1] = __builtin_amdgcn_mfma_f32_16x16x32_f16(a1, bf, acc[j][1], 0, 0, 0);
            }
        }
    };

    load_group(g0, 0);
    #pragma unroll 1
    for (int gi = 0; gi < GPS; gi += 2) {      // GPS = 4 -> 2 iterations
        load_group(g0 + gi + 1, 1);
        compute_group(gi, 0);
        if (gi + 2 < GPS) load_group(g0 + gi + 2, 0);
        compute_group(gi + 1, 1);
    }

    // Split-K accumulate: out += acc + bias/NSEG  (exact: NSEG is a power of 2)
    #pragma unroll
    for (int j = 0; j < 4; ++j) {
        const int n  = n0 + j * 16 + l16;
        const float bb = bias[n] * (1.0f / NSEG);
        #pragma unroll
        for (int m = 0; m < 2; ++m)
            #pragma unroll
            for (int r = 0; r < 4; ++r) {
                const int t = m * 16 + quad * 4 + r;
                unsafeAtomicAdd(out + (size_t)t * NDIM + n, acc[j][m][r] + bb);
            }
    }
}

extern "C" void kernel_launch(void* const* d_in, const int* in_sizes, int n_in,
                              void* d_out, int out_size, void* d_ws, size_t ws_size,
                              hipStream_t stream)
{
    const float* x  = (const float*)d_in[0];   // (32, 8192) f32 (fp16 promoted)
    const int* qweight = (const int*)d_in[1];  // (1024, 28672) i32
    const int* qzeros  = (const int*)d_in[2];  // (64, 3584) i32
    const float* sc = (const float*)d_in[3];   // (64, 28672) f32
    const float* bs = (const float*)d_in[4];   // (28672,) f32
    float* out      = (float*)d_out;           // (32, 28672) f32
    (void)d_ws; (void)ws_size;

    exllama_gemm_lds_atomic<<<dim3(NDIM / 256, NSEG), 256, 0, stream>>>(
        qweight, qzeros, sc, x, bs, out);
}

// Round 7
// 208.092 us; speedup vs baseline: 1.1522x; 1.0448x over previous
//
#include <hip/hip_runtime.h>

// ExLlama q4: T=32, K=8192, N=28672, group=128.
// Harness promotes fp16 reference arrays to float32; output is float32.
#define T_TOK   32
#define KDIM    8192
#define NDIM    28672
#define NGRP    64        // K / 128
#define NZWORDS 3584      // N / 8
#define NSEG    16        // K-segments (blockIdx.y)
#define SEGK    (KDIM / NSEG)    // 512
#define GPS     (NGRP / NSEG)    // 4 groups per segment
#define XROW    (SEGK + 8)       // padded LDS row stride (fp16): 520

typedef _Float16 half8  __attribute__((ext_vector_type(8)));
typedef _Float16 half2v __attribute__((ext_vector_type(2)));
typedef float    f32x4  __attribute__((ext_vector_type(4)));
typedef unsigned uint4v __attribute__((ext_vector_type(4)));

// One wave: 64 columns (4 n-tiles of 16) x 32 tokens over one K-segment.
// MFMA 16x16x32 f16: A[m=lane&15][k=quad*8+j], B[k=quad*8+j][n=lane&15],
// C/D: col=lane&15, row=quad*4+reg.
// Within each 8-k block both A and B use k-permutation [0,4,1,5,2,6,3,7]:
//   A: packed at LDS-staging time via v_cvt_pkrtz (free);
//   B: pair = ((w>>4i)&0x000F000F)|0x64006400 = fp16 (1024+q_i, 1024+q_{i+4});
//      b = (pair + (-(1025+z))) * s   (integer part exact in fp16).
// DEEP PREFETCH: the lane's ENTIRE K-segment of qweight (GPS*16 = 64 dwords)
// plus scales/zeros is loaded into registers up front, BEFORE x staging.
// The x-staging vmcnt drain + barrier then overlaps the qweight latency, and
// the compute loop runs with zero global-memory stalls (LDS + regs only).
// Split-K via fp32 HW atomics; bias/NSEG folded into every segment (exact).
__global__ __launch_bounds__(256)
void exllama_gemm_deep(const int*   __restrict__ qweight,
                       const int*   __restrict__ qzeros,
                       const float* __restrict__ scales,
                       const float* __restrict__ x,
                       const float* __restrict__ bias,
                       float*       __restrict__ out)
{
    __shared__ alignas(16) _Float16 xs[T_TOK * XROW];   // 33.3 KB

    const int tid  = threadIdx.x;
    const int lane = tid & 63;
    const int wav  = tid >> 6;
    const int quad = lane >> 4;
    const int l16  = lane & 15;
    const int seg  = blockIdx.y;
    const int n0   = blockIdx.x * 256 + wav * 64;

    int nc[4];
    #pragma unroll
    for (int j = 0; j < 4; ++j) nc[j] = n0 + j * 16 + l16;

    const int g0 = seg * GPS;

    // ---- deep prefetch: whole segment of qweight + scales/zeros ----
    unsigned qw[GPS][16];
    half2v   sp[GPS][4], cp[GPS][4];
    #pragma unroll
    for (int g = 0; g < GPS; ++g) {
        const size_t rb = (size_t)((g0 + g) * 16 + quad) * NDIM;
        #pragma unroll
        for (int c = 0; c < 4; ++c)
            #pragma unroll
            for (int j = 0; j < 4; ++j)
                qw[g][c * 4 + j] = (unsigned)qweight[rb + (size_t)(c * 4) * NDIM + nc[j]];
    }
    #pragma unroll
    for (int g = 0; g < GPS; ++g) {
        #pragma unroll
        for (int j = 0; j < 4; ++j) {
            float s  = scales[(size_t)(g0 + g) * NDIM + nc[j]];
            int   zw = qzeros[(size_t)(g0 + g) * NZWORDS + (nc[j] >> 3)];
            int   z  = (zw >> ((nc[j] & 7) * 4)) & 15;
            _Float16 sh = (_Float16)s;
            _Float16 ch = (_Float16)(float)(-(1025 + z));
            sp[g][j] = (half2v){sh, sh};
            cp[g][j] = (half2v){ch, ch};
        }
    }

    // ---- stage x segment into LDS as fp16, pair-permuted [i, i+4] ----
    {
        const int kseg0 = seg * SEGK;
        #pragma unroll
        for (int it = 0; it < (T_TOK * SEGK) / (256 * 8); ++it) {   // 8 iters
            const int e  = it * 2048 + tid * 8;
            const int t  = e >> 9;           // SEGK = 512
            const int kl = e & (SEGK - 1);
            const float* xp = x + (size_t)t * KDIM + kseg0 + kl;
            f32x4 lo = *(const f32x4*)xp;
            f32x4 hi = *(const f32x4*)(xp + 4);
            uint4v u;
            #pragma unroll
            for (int j = 0; j < 4; ++j)
                u[j] = __builtin_bit_cast(unsigned,
                          __builtin_amdgcn_cvt_pkrtz(lo[j], hi[j]));
            *(uint4v*)(xs + t * XROW + kl) = u;
        }
    }
    __syncthreads();

    f32x4 acc[4][2];
    #pragma unroll
    for (int j = 0; j < 4; ++j)
        #pragma unroll
        for (int m = 0; m < 2; ++m)
            acc[j][m] = (f32x4){0.f, 0.f, 0.f, 0.f};

    // ---- compute: registers + LDS only, no global traffic ----
    #pragma unroll
    for (int g = 0; g < GPS; ++g) {
        #pragma unroll
        for (int c = 0; c < 4; ++c) {
            const int kloc = g * 128 + c * 32 + quad * 8;
            half8 a0 = *(const half8*)(xs + l16 * XROW + kloc);
            half8 a1 = *(const half8*)(xs + (l16 + 16) * XROW + kloc);
            #pragma unroll
            for (int j = 0; j < 4; ++j) {
                const unsigned w = qw[g][c * 4 + j];
                uint4v bu;
                #pragma unroll
                for (int i = 0; i < 4; ++i) {
                    unsigned t = ((w >> (4 * i)) & 0x000F000Fu) | 0x64006400u;
                    half2v th = __builtin_bit_cast(half2v, t);
                    half2v r  = (th + cp[g][j]) * sp[g][j];
                    bu[i] = __builtin_bit_cast(unsigned, r);
                }
                half8 bf = __builtin_bit_cast(half8, bu);
                acc[j][0] = __builtin_amdgcn_mfma_f32_16x16x32_f16(a0, bf, acc[j][0], 0, 0, 0);
                acc[j][1] = __builtin_amdgcn_mfma_f32_16x16x32_f16(a1, bf, acc[j][1], 0, 0, 0);
            }
        }
    }

    // Split-K accumulate: out += acc + bias/NSEG  (exact: NSEG is a power of 2)
    #pragma unroll
    for (int j = 0; j < 4; ++j) {
        const int n  = n0 + j * 16 + l16;
        const float bb = bias[n] * (1.0f / NSEG);
        #pragma unroll
        for (int m = 0; m < 2; ++m)
            #pragma unroll
            for (int r = 0; r < 4; ++r) {
                const int t = m * 16 + quad * 4 + r;
                unsafeAtomicAdd(out + (size_t)t * NDIM + n, acc[j][m][r] + bb);
            }
    }
}

extern "C" void kernel_launch(void* const* d_in, const int* in_sizes, int n_in,
                              void* d_out, int out_size, void* d_ws, size_t ws_size,
                              hipStream_t stream)
{
    const float* x  = (const float*)d_in[0];   // (32, 8192) f32 (fp16 promoted)
    const int* qweight = (const int*)d_in[1];  // (1024, 28672) i32
    const int* qzeros  = (const int*)d_in[2];  // (64, 3584) i32
    const float* sc = (const float*)d_in[3];   // (64, 28672) f32
    const float* bs = (const float*)d_in[4];   // (28672,) f32
    float* out      = (float*)d_out;           // (32, 28672) f32
    (void)d_ws; (void)ws_size;

    exllama_gemm_deep<<<dim3(NDIM / 256, NSEG), 256, 0, stream>>>(
        qweight, qzeros, sc, x, bs, out);
}

// Round 8
// 202.301 us; speedup vs baseline: 1.1852x; 1.0286x over previous
//
#include <hip/hip_runtime.h>

// ExLlama q4: T=32, K=8192, N=28672, group=128.
// Harness promotes fp16 reference arrays to float32; output is float32.
#define T_TOK   32
#define KDIM    8192
#define NDIM    28672
#define NGRP    64        // K / 128
#define NZWORDS 3584      // N / 8
#define NSEG    16        // K-segments (blockIdx.y)
#define SEGK    (KDIM / NSEG)    // 512
#define GPS     (NGRP / NSEG)    // 4 groups per segment
#define XROW    (SEGK + 8)       // padded LDS row stride (fp16): 520

typedef _Float16 half8  __attribute__((ext_vector_type(8)));
typedef _Float16 half2v __attribute__((ext_vector_type(2)));
typedef float    f32x4  __attribute__((ext_vector_type(4)));
typedef unsigned uint4v __attribute__((ext_vector_type(4)));

// One wave: 64 columns (4 n-tiles of 16) x 32 tokens over one K-segment.
// MFMA 16x16x32 f16: A[m=lane&15][k=quad*8+j], B[k=quad*8+j][n=lane&15],
// C/D: col=lane&15, row=quad*4+reg.
// Within each 8-k block both A and B use k-permutation [0,4,1,5,2,6,3,7]:
//   A: packed at LDS-staging time via v_cvt_pkrtz (free);
//   B: pair = ((w>>4i)&0x000F000F)|0x64006400 = fp16 (1024+q_i, 1024+q_{i+4});
//      b = (pair + (-(1025+z))) * s   (integer part exact in fp16).
// Deep prefetch: whole segment of qweight (+scales/zeros) issued before x
// staging; the staging barrier's vmcnt drain absorbs all load latency, and
// the compute loop runs stall-free from registers + LDS.
// EPILOGUE EXPERIMENT (vs R7): plain coalesced ws stores + separate reduce
// kernel instead of 14.7M contended fp32 atomics (suspected ~40+ us cost).
template<bool ATOMIC>
__global__ __launch_bounds__(256)
void exllama_gemm_deep(const int*   __restrict__ qweight,
                       const int*   __restrict__ qzeros,
                       const float* __restrict__ scales,
                       const float* __restrict__ x,
                       const float* __restrict__ bias,
                       float*       __restrict__ ws,
                       float*       __restrict__ out)
{
    __shared__ alignas(16) _Float16 xs[T_TOK * XROW];   // 33.3 KB

    const int tid  = threadIdx.x;
    const int lane = tid & 63;
    const int wav  = tid >> 6;
    const int quad = lane >> 4;
    const int l16  = lane & 15;
    const int seg  = blockIdx.y;
    const int n0   = blockIdx.x * 256 + wav * 64;

    int nc[4];
    #pragma unroll
    for (int j = 0; j < 4; ++j) nc[j] = n0 + j * 16 + l16;

    const int g0 = seg * GPS;

    // ---- deep prefetch: whole segment of qweight + scales/zeros ----
    unsigned qw[GPS][16];
    half2v   sp[GPS][4], cp[GPS][4];
    #pragma unroll
    for (int g = 0; g < GPS; ++g) {
        const size_t rb = (size_t)((g0 + g) * 16 + quad) * NDIM;
        #pragma unroll
        for (int c = 0; c < 4; ++c)
            #pragma unroll
            for (int j = 0; j < 4; ++j)
                qw[g][c * 4 + j] = (unsigned)qweight[rb + (size_t)(c * 4) * NDIM + nc[j]];
    }
    #pragma unroll
    for (int g = 0; g < GPS; ++g) {
        #pragma unroll
        for (int j = 0; j < 4; ++j) {
            float s  = scales[(size_t)(g0 + g) * NDIM + nc[j]];
            int   zw = qzeros[(size_t)(g0 + g) * NZWORDS + (nc[j] >> 3)];
            int   z  = (zw >> ((nc[j] & 7) * 4)) & 15;
            _Float16 sh = (_Float16)s;
            _Float16 ch = (_Float16)(float)(-(1025 + z));
            sp[g][j] = (half2v){sh, sh};
            cp[g][j] = (half2v){ch, ch};
        }
    }

    // ---- stage x segment into LDS as fp16, pair-permuted [i, i+4] ----
    {
        const int kseg0 = seg * SEGK;
        #pragma unroll
        for (int it = 0; it < (T_TOK * SEGK) / (256 * 8); ++it) {   // 8 iters
            const int e  = it * 2048 + tid * 8;
            const int t  = e >> 9;           // SEGK = 512
            const int kl = e & (SEGK - 1);
            const float* xp = x + (size_t)t * KDIM + kseg0 + kl;
            f32x4 lo = *(const f32x4*)xp;
            f32x4 hi = *(const f32x4*)(xp + 4);
            uint4v u;
            #pragma unroll
            for (int j = 0; j < 4; ++j)
                u[j] = __builtin_bit_cast(unsigned,
                          __builtin_amdgcn_cvt_pkrtz(lo[j], hi[j]));
            *(uint4v*)(xs + t * XROW + kl) = u;
        }
    }
    __syncthreads();

    f32x4 acc[4][2];
    #pragma unroll
    for (int j = 0; j < 4; ++j)
        #pragma unroll
        for (int m = 0; m < 2; ++m)
            acc[j][m] = (f32x4){0.f, 0.f, 0.f, 0.f};

    // ---- compute: registers + LDS only, no global traffic ----
    #pragma unroll
    for (int g = 0; g < GPS; ++g) {
        #pragma unroll
        for (int c = 0; c < 4; ++c) {
            const int kloc = g * 128 + c * 32 + quad * 8;
            half8 a0 = *(const half8*)(xs + l16 * XROW + kloc);
            half8 a1 = *(const half8*)(xs + (l16 + 16) * XROW + kloc);
            #pragma unroll
            for (int j = 0; j < 4; ++j) {
                const unsigned w = qw[g][c * 4 + j];
                uint4v bu;
                #pragma unroll
                for (int i = 0; i < 4; ++i) {
                    unsigned t = ((w >> (4 * i)) & 0x000F000Fu) | 0x64006400u;
                    half2v th = __builtin_bit_cast(half2v, t);
                    half2v r  = (th + cp[g][j]) * sp[g][j];
                    bu[i] = __builtin_bit_cast(unsigned, r);
                }
                half8 bf = __builtin_bit_cast(half8, bu);
                acc[j][0] = __builtin_amdgcn_mfma_f32_16x16x32_f16(a0, bf, acc[j][0], 0, 0, 0);
                acc[j][1] = __builtin_amdgcn_mfma_f32_16x16x32_f16(a1, bf, acc[j][1], 0, 0, 0);
            }
        }
    }

    if (ATOMIC) {
        #pragma unroll
        for (int j = 0; j < 4; ++j) {
            const int n  = n0 + j * 16 + l16;
            const float bb = bias[n] * (1.0f / NSEG);
            #pragma unroll
            for (int m = 0; m < 2; ++m)
                #pragma unroll
                for (int r = 0; r < 4; ++r) {
                    const int t = m * 16 + quad * 4 + r;
                    unsafeAtomicAdd(out + (size_t)t * NDIM + n, acc[j][m][r] + bb);
                }
        }
    } else {
        float* wsp = ws + (size_t)seg * (T_TOK * NDIM);
        #pragma unroll
        for (int j = 0; j < 4; ++j) {
            const int n = n0 + j * 16 + l16;
            #pragma unroll
            for (int m = 0; m < 2; ++m)
                #pragma unroll
                for (int r = 0; r < 4; ++r) {
                    const int t = m * 16 + quad * 4 + r;
                    wsp[(size_t)t * NDIM + n] = acc[j][m][r];
                }
        }
    }
}

__global__ __launch_bounds__(256)
void reduce_bias(const float* __restrict__ ws,
                 const float* __restrict__ bias,
                 float*       __restrict__ out)
{
    const int e = (blockIdx.x * 256 + threadIdx.x) * 4;  // 4 consecutive, one row
    const int n = e % NDIM;
    f32x4 sum = (f32x4){0.f, 0.f, 0.f, 0.f};
    #pragma unroll
    for (int s = 0; s < NSEG; ++s)
        sum += *(const f32x4*)(ws + (size_t)s * (T_TOK * NDIM) + e);
    f32x4 bb = *(const f32x4*)(bias + n);
    *(f32x4*)(out + e) = sum + bb;
}

extern "C" void kernel_launch(void* const* d_in, const int* in_sizes, int n_in,
                              void* d_out, int out_size, void* d_ws, size_t ws_size,
                              hipStream_t stream)
{
    const float* x  = (const float*)d_in[0];   // (32, 8192) f32 (fp16 promoted)
    const int* qweight = (const int*)d_in[1];  // (1024, 28672) i32
    const int* qzeros  = (const int*)d_in[2];  // (64, 3584) i32
    const float* sc = (const float*)d_in[3];   // (64, 28672) f32
    const float* bs = (const float*)d_in[4];   // (28672,) f32
    float* out      = (float*)d_out;           // (32, 28672) f32

    const size_t need = (size_t)NSEG * T_TOK * NDIM * sizeof(float);  // 58.7 MB
    if (ws_size >= need) {
        exllama_gemm_deep<false><<<dim3(NDIM / 256, NSEG), 256, 0, stream>>>(
            qweight, qzeros, sc, x, bs, (float*)d_ws, out);
        reduce_bias<<<(T_TOK * NDIM) / (256 * 4), 256, 0, stream>>>(
            (const float*)d_ws, bs, out);
    } else {
        exllama_gemm_deep<true><<<dim3(NDIM / 256, NSEG), 256, 0, stream>>>(
            qweight, qzeros, sc, x, bs, nullptr, out);
    }
}